// Round 7
// baseline (376.461 us; speedup 1.0000x reference)
//
#include <hip/hip_runtime.h>
#include <hip/hip_bf16.h>
#include <math.h>

// Problem constants (B=2, C=256, H=W=64, heads=8, hd=32, groups=32, hid=64)
#define NB 2
#define NC 256
#define NHEAD 8
#define HD 32
#define NPIX 4096
#define GEPS 1e-5f
#define NCHUNK 2          // j-split factor for attention (linear softmax => exact)
#define JLEN (NPIX / NCHUNK)

typedef short bf16x8 __attribute__((ext_vector_type(8)));
typedef float f32x4 __attribute__((ext_vector_type(4)));

union U16x8 { uint4 u4; uint2 u2[2]; unsigned u32[4]; unsigned short us[8]; bf16x8 v; };

__device__ inline unsigned short tobf(float f) {  // round-to-nearest-even
  union { float f; unsigned u; } c; c.f = f;
  return (unsigned short)((c.u + 0x7FFFu + ((c.u >> 16) & 1u)) >> 16);
}
__device__ inline unsigned packtrunc(float lo, float hi) {  // truncating bf16 pack
  return (__float_as_uint(lo) >> 16) | (__float_as_uint(hi) & 0xFFFF0000u);
}

// ---------------------------------------------------------------------------
// Dtype detection (bf16 vs fp32 inputs).
// ---------------------------------------------------------------------------
__global__ void detect_kernel(const void* __restrict__ x, int* __restrict__ flag) {
  int lane = threadIdx.x;
  const unsigned short* u = (const unsigned short*)x;
  unsigned short h = u[2 * lane];
  unsigned e = (h >> 7) & 0xFFu;
  int weird = (e < 113u || e > 140u) ? 1 : 0;
  unsigned long long mask = __ballot(weird);
  if (lane == 0) flag[0] = (__popcll(mask) > 16) ? 0 : 1;
}

struct ConvArgs { const void* src[13]; int off[14]; };

__global__ __launch_bounds__(256) void convert_all_kernel(ConvArgs a, float* __restrict__ dstbase,
                                                          const int* __restrict__ flag, int total) {
  int i = blockIdx.x * 256 + threadIdx.x;
  if (i >= total) return;
  int s = 0;
  while (i >= a.off[s + 1]) ++s;
  int local = i - a.off[s];
  if (*flag) {
    unsigned v = ((const unsigned short*)a.src[s])[local];
    dstbase[i] = __uint_as_float(v << 16);
  } else {
    dstbase[i] = ((const float*)a.src[s])[local];
  }
}

// ---------------------------------------------------------------------------
// Prep: weights fp32->bf16 + qscale (temp*log2e for o<256 else 1).
// ---------------------------------------------------------------------------
__global__ __launch_bounds__(256) void prep_kernel(
    const float* __restrict__ wqkv, const float* __restrict__ wout,
    const float* __restrict__ wm1, const float* __restrict__ wm2,
    const float* __restrict__ temp,
    unsigned short* __restrict__ wqkv_b, unsigned short* __restrict__ wout_b,
    unsigned short* __restrict__ wm1_b, unsigned short* __restrict__ wm2_b,
    float* __restrict__ qscale) {
  int i = blockIdx.x * 256 + threadIdx.x;
  if (i < 196608) wqkv_b[i] = tobf(wqkv[i]);
  else if (i < 262144) wout_b[i - 196608] = tobf(wout[i - 196608]);
  else if (i < 278528) wm1_b[i - 262144] = tobf(wm1[i - 262144]);
  else if (i < 294912) wm2_b[i - 278528] = tobf(wm2[i - 278528]);
  if (i < 768) {
    if (i < 256) {
      float tc = fminf(fmaxf(temp[i >> 5], 1e-4f), 10.f);
      qscale[i] = tc * 1.4426950408889634f;
    } else qscale[i] = 1.0f;
  }
}

// ---------------------------------------------------------------------------
// GroupNorm stats, NO atomics: 256 blocks store deterministic partials.
// ---------------------------------------------------------------------------
__global__ __launch_bounds__(256) void gn_stats_kernel(const float* __restrict__ in,
                                                       float* __restrict__ part) {
  int blk = blockIdx.x;          // bg = blk>>2, quarter = blk&3
  int bg = blk >> 2, q = blk & 3;
  const float* base = in + (size_t)bg * 32768 + q * 8192;
  int t = threadIdx.x;
  float s = 0.f, s2 = 0.f;
  for (int i = t; i < 8192; i += 256) { float v = base[i]; s += v; s2 += v * v; }
  __shared__ float rs[256], rq[256];
  rs[t] = s; rq[t] = s2;
  __syncthreads();
  for (int o = 128; o > 0; o >>= 1) {
    if (t < o) { rs[t] += rs[t + o]; rq[t] += rq[t + o]; }
    __syncthreads();
  }
  if (t == 0) { part[blk * 2] = rs[0]; part[blk * 2 + 1] = rq[0]; }
}

// ---------------------------------------------------------------------------
// GroupNorm apply + transpose to bf16 pixel-major [p][256]. 512 blocks.
// ---------------------------------------------------------------------------
__global__ __launch_bounds__(256) void gn_apply_kernel(
    const float* __restrict__ in, const float* __restrict__ part,
    const float* __restrict__ gamma, const float* __restrict__ beta,
    unsigned short* __restrict__ outt) {
  int t = threadIdx.x;
  int p = blockIdx.x * 16 + (t & 15);
  int cg = t >> 4;
  int b = p >> 12, n = p & 4095;
  const float* src = in + ((size_t)b * NC + cg * 16) * NPIX + n;
  U16x8 lo, hi;
#pragma unroll
  for (int cc = 0; cc < 16; ++cc) {
    int c = cg * 16 + cc;
    int bg = b * 32 + (c >> 3);
    const float* pp = &part[bg * 8];   // [q][2] partials, q<4
    float s  = (pp[0] + pp[2]) + (pp[4] + pp[6]);
    float s2 = (pp[1] + pp[3]) + (pp[5] + pp[7]);
    float mean = s * (1.f / 32768.f);
    float inv = rsqrtf(s2 * (1.f / 32768.f) - mean * mean + GEPS);
    float gg = gamma[c] * inv;
    float vv = (src[(size_t)cc * NPIX] - mean) * gg + beta[c];
    if (cc < 8) lo.us[cc] = tobf(vv); else hi.us[cc - 8] = tobf(vv);
  }
  unsigned short* dst = outt + (size_t)p * NC + cg * 16;
  *(uint4*)dst = lo.u4;
  *(uint4*)(dst + 8) = hi.u4;
}

// ---------------------------------------------------------------------------
// bf16 MFMA GEMM, LDS-free (unchanged from round 6).
// ---------------------------------------------------------------------------
template <int K, int OT, int EPI, int ACT, int OSTR>
__global__ __launch_bounds__(256) void mfma_gemm(
    const unsigned short* __restrict__ W, const unsigned short* __restrict__ X,
    const float* __restrict__ scale, const float* __restrict__ bias,
    const float* __restrict__ res, void* __restrict__ out,
    void* __restrict__ out2, void* __restrict__ out3,
    const int* __restrict__ flag) {
  int t = threadIdx.x;
  int w = t >> 6, lane = t & 63, l16 = lane & 15, quad = lane >> 4;
  int p = blockIdx.x * 16 + l16;
  int ob = blockIdx.y * (64 * OT) + w * (16 * OT);
  const unsigned short* xrow = X + (size_t)p * K + quad * 8;
  f32x4 acc[OT] = {};
#pragma unroll
  for (int k0 = 0; k0 < K; k0 += 32) {
    U16x8 bfr; bfr.u4 = *(const uint4*)(xrow + k0);
#pragma unroll
    for (int ot = 0; ot < OT; ++ot) {
      U16x8 af;
      af.u4 = *(const uint4*)(W + (size_t)(ob + ot * 16 + l16) * K + k0 + quad * 8);
      acc[ot] = __builtin_amdgcn_mfma_f32_16x16x32_bf16(af.v, bfr.v, acc[ot], 0, 0, 0);
    }
  }
  int b = p >> 12, n = p & 4095;
  int wbf = (EPI == 2) ? *flag : 0;
#pragma unroll
  for (int ot = 0; ot < OT; ++ot) {
    int oc = ob + ot * 16 + quad * 4;
    float v[4];
#pragma unroll
    for (int r = 0; r < 4; ++r) {
      float vv = acc[ot][r];
      if (scale) vv *= scale[oc + r];
      if (bias) vv += bias[oc + r];
      if (ACT == 1) vv = 0.5f * vv * (1.f + erff(vv * 0.70710678118654752f));
      v[r] = vv;
    }
    if (EPI == 0) {
      uint2 pk;
      pk.x = (unsigned)tobf(v[0]) | ((unsigned)tobf(v[1]) << 16);
      pk.y = (unsigned)tobf(v[2]) | ((unsigned)tobf(v[3]) << 16);
      *(uint2*)((unsigned short*)out + (size_t)p * OSTR + oc) = pk;
    } else if (EPI == 3) {
      int sec = oc >> 8;  // block-uniform: 0=Q, 1=K, 2=V
      int c = oc & 255;
      if (sec < 2) {
        int hh = c >> 5, d = c & 31;
        unsigned short* base = (unsigned short*)(sec == 0 ? out : out2);
        uint2 pk;
        pk.x = (unsigned)tobf(v[0]) | ((unsigned)tobf(v[1]) << 16);
        pk.y = (unsigned)tobf(v[2]) | ((unsigned)tobf(v[3]) << 16);
        *(uint2*)(base + ((size_t)(b * NHEAD + hh) * NPIX + n) * HD + d) = pk;
      } else {
        unsigned short* vsb = (unsigned short*)out3;
#pragma unroll
        for (int r = 0; r < 4; ++r)
          vsb[((size_t)(b * NC + c + r)) * NPIX + n] = tobf(v[r]);
      }
    } else {
#pragma unroll
      for (int r = 0; r < 4; ++r) {
        size_t oidx = ((size_t)(b * NC + oc + r)) * NPIX + n;
        float vv = v[r] + res[oidx];
        if (EPI == 2) {
          if (wbf) ((__hip_bfloat16*)out)[oidx] = __float2bfloat16(vv);
          else ((float*)out)[oidx] = vv;
        } else {
          ((float*)out)[oidx] = vv;
        }
      }
    }
  }
}

// ---------------------------------------------------------------------------
// MFMA flash attention v5 — j-split for occupancy. No-max softmax is linear
// in j, so each block computes exact partials over its j-chunk:
//   pO[chunk][pair][d][i] = sum_j P*V^T,  pl[chunk][pair][i] = sum_j P.
// Grid (64*NCHUNK, 8, 2) = 2048 blocks = 8/CU = 8 waves/SIMD (the cap).
// Static round-4 structure otherwise (single prefetch, compile-time indices).
// ---------------------------------------------------------------------------
__global__ __launch_bounds__(256) void attn5_kernel(
    const unsigned short* __restrict__ qn, const unsigned short* __restrict__ kn,
    const unsigned short* __restrict__ vs, float* __restrict__ pO,
    float* __restrict__ pl) {
  int bx = blockIdx.x;
  int iblk = bx & 63, chunk = bx >> 6;
  int i0 = iblk * 64;
  int jstart = chunk * JLEN;
  int h = blockIdx.y, b = blockIdx.z;
  int bh = b * NHEAD + h;
  int t = threadIdx.x;
  int w = t >> 6, lane = t & 63, l16 = lane & 15, quad = lane >> 4;

  __shared__ unsigned short Pl[4][16][72];

  U16x8 qf;
  qf.u4 = *(const uint4*)(qn + ((size_t)bh * NPIX + i0 + w * 16 + l16) * HD + quad * 8);
  U16x8 ones;
#pragma unroll
  for (int j = 0; j < 8; ++j) ones.us[j] = 0x3F80;

  const unsigned short* kbase = kn + (size_t)bh * NPIX * HD + quad * 8;
  const unsigned short* vrow0 = vs + ((size_t)(b * NC + h * HD + l16)) * NPIX + quad * 8;
  const unsigned short* vrow1 = vrow0 + (size_t)16 * NPIX;

  f32x4 o0 = {0.f, 0.f, 0.f, 0.f}, o1 = {0.f, 0.f, 0.f, 0.f};
  f32x4 lacc = {0.f, 0.f, 0.f, 0.f};
  const f32x4 zf = {0.f, 0.f, 0.f, 0.f};

  U16x8 kf[4], vf0[2], vf1[2];
#pragma unroll
  for (int jt = 0; jt < 4; ++jt)
    kf[jt].u4 = *(const uint4*)(kbase + (size_t)(jstart + jt * 16 + l16) * HD);
#pragma unroll
  for (int ks = 0; ks < 2; ++ks) {
    vf0[ks].u4 = *(const uint4*)(vrow0 + jstart + ks * 32);
    vf1[ks].u4 = *(const uint4*)(vrow1 + jstart + ks * 32);
  }

  for (int jl = 0; jl < JLEN; jl += 64) {
    int jn = jstart + ((jl + 64) & (JLEN - 1));  // wraps on last iter
    U16x8 kp[4], v0p[2], v1p[2];
#pragma unroll
    for (int jt = 0; jt < 4; ++jt)
      kp[jt].u4 = *(const uint4*)(kbase + (size_t)(jn + jt * 16 + l16) * HD);
#pragma unroll
    for (int ks = 0; ks < 2; ++ks) {
      v0p[ks].u4 = *(const uint4*)(vrow0 + jn + ks * 32);
      v1p[ks].u4 = *(const uint4*)(vrow1 + jn + ks * 32);
    }
    f32x4 st[4];
#pragma unroll
    for (int jt = 0; jt < 4; ++jt)
      st[jt] = __builtin_amdgcn_mfma_f32_16x16x32_bf16(kf[jt].v, qf.v, zf, 0, 0, 0);
#pragma unroll
    for (int jt = 0; jt < 4; ++jt) {
      uint2 pk;
      pk.x = packtrunc(__builtin_amdgcn_exp2f(st[jt][0]), __builtin_amdgcn_exp2f(st[jt][1]));
      pk.y = packtrunc(__builtin_amdgcn_exp2f(st[jt][2]), __builtin_amdgcn_exp2f(st[jt][3]));
      *(uint2*)&Pl[w][l16][jt * 16 + quad * 4] = pk;
    }
#pragma unroll
    for (int ks = 0; ks < 2; ++ks) {
      U16x8 pb; pb.u4 = *(const uint4*)&Pl[w][l16][ks * 32 + quad * 8];
      o0 = __builtin_amdgcn_mfma_f32_16x16x32_bf16(vf0[ks].v, pb.v, o0, 0, 0, 0);
      o1 = __builtin_amdgcn_mfma_f32_16x16x32_bf16(vf1[ks].v, pb.v, o1, 0, 0, 0);
      lacc = __builtin_amdgcn_mfma_f32_16x16x32_bf16(ones.v, pb.v, lacc, 0, 0, 0);
    }
#pragma unroll
    for (int jt = 0; jt < 4; ++jt) kf[jt] = kp[jt];
#pragma unroll
    for (int ks = 0; ks < 2; ++ks) { vf0[ks] = v0p[ks]; vf1[ks] = v1p[ks]; }
  }

  // Partial store. C-layout: col i = l16 (wave covers i0 + w*16 + l16),
  // rows d = quad*4+r (o0), 16+quad*4+r (o1).
  int pr = bh * 64 + iblk;
  float* ob = pO + ((size_t)chunk * 1024 + pr) * 2048;
  int icol = w * 16 + l16;
#pragma unroll
  for (int r = 0; r < 4; ++r) {
    ob[(quad * 4 + r) * 64 + icol] = o0[r];
    ob[(16 + quad * 4 + r) * 64 + icol] = o1[r];
  }
  if (quad == 0)
    pl[((size_t)chunk * 1024 + pr) * 64 + icol] = lacc[0];
}

// ---------------------------------------------------------------------------
// Combine j-chunk partials: O = sum_c pO, l = sum_c pl; out = O/l -> bf16
// pixel-major aout_t[p][256]. Grid 1024 (one block per (bh,iblk) pair).
// ---------------------------------------------------------------------------
__global__ __launch_bounds__(256) void attn_combine_kernel(
    const float* __restrict__ pO, const float* __restrict__ pl,
    unsigned short* __restrict__ aout_t) {
  int pr = blockIdx.x;
  int b = pr >> 9, h = (pr >> 6) & 7, iblk = pr & 63;
  int t = threadIdx.x;
  int i = t & 63, dg = t >> 6;
  float l = 0.f;
#pragma unroll
  for (int c = 0; c < NCHUNK; ++c) l += pl[((size_t)c * 1024 + pr) * 64 + i];
  float rinv = 1.f / l;
  U16x8 pk;
#pragma unroll
  for (int dd = 0; dd < 8; ++dd) {
    int d = dg * 8 + dd;
    float v = 0.f;
#pragma unroll
    for (int c = 0; c < NCHUNK; ++c)
      v += pO[((size_t)c * 1024 + pr) * 2048 + d * 64 + i];
    pk.us[dd] = tobf(v * rinv);
  }
  *(uint4*)(aout_t + ((size_t)b * NPIX + iblk * 64 + i) * NC + h * 32 + dg * 8) = pk.u4;
}

// ---------------------------------------------------------------------------
// Launch pipeline. (off is in FLOAT units; bf16 buffers advance by N/2.)
// ---------------------------------------------------------------------------
extern "C" void kernel_launch(void* const* d_in, const int* in_sizes, int n_in,
                              void* d_out, int out_size, void* d_ws, size_t ws_size,
                              hipStream_t stream) {
  float* ws = (float*)d_ws;
  int* flag = (int*)d_ws;
  size_t off = 16;
  float* x_f    = ws + off; off += (size_t)NB * NC * NPIX;
  float* wqkv_f = ws + off; off += 768 * 256;
  float* wout_f = ws + off; off += 256 * 256;
  float* bout_f = ws + off; off += 256;
  float* temp_f = ws + off; off += 8;
  float* g1_f   = ws + off; off += 256;
  float* be1_f  = ws + off; off += 256;
  float* g2_f   = ws + off; off += 256;
  float* be2_f  = ws + off; off += 256;
  float* wm1_f  = ws + off; off += 64 * 256;
  float* bm1_f  = ws + off; off += 64;
  float* wm2_f  = ws + off; off += 256 * 64;
  float* bm2_f  = ws + off; off += 256;
  float* xres   = ws + off; off += (size_t)NB * NC * NPIX;
  unsigned short* xn_t   = (unsigned short*)(ws + off); off += 1048576;  // [8192][256]
  unsigned short* qn     = (unsigned short*)(ws + off); off += 1048576;  // [16][4096][32]
  unsigned short* kn     = (unsigned short*)(ws + off); off += 1048576;  // [16][4096][32]
  unsigned short* vs     = (unsigned short*)(ws + off); off += 1048576;  // [2][256][4096]
  unsigned short* aout_t = (unsigned short*)(ws + off); off += 1048576;  // [8192][256]
  unsigned short* ybuf_t = (unsigned short*)(ws + off); off += 1048576;  // [8192][256]
  unsigned short* h_t    = (unsigned short*)(ws + off); off += 262144;   // [8192][64]
  unsigned short* wqkv_b = (unsigned short*)(ws + off); off += 98304;
  unsigned short* wout_b = (unsigned short*)(ws + off); off += 32768;
  unsigned short* wm1_b  = (unsigned short*)(ws + off); off += 8192;
  unsigned short* wm2_b  = (unsigned short*)(ws + off); off += 8192;
  float* qscale = ws + off; off += 768;
  float* part1  = ws + off; off += 512;   // GN1 partials [256][2]
  float* part2  = ws + off; off += 512;   // GN2 partials
  float* pO     = ws + off; off += (size_t)NCHUNK * 1024 * 2048;  // attn partial O
  float* plb    = ws + off; off += (size_t)NCHUNK * 1024 * 64;    // attn partial l

  detect_kernel<<<1, 64, 0, stream>>>(d_in[0], flag);

  ConvArgs ca;
  int acc = 0;
  for (int i = 0; i < 13; ++i) {
    ca.src[i] = d_in[i];
    ca.off[i] = acc;
    acc += (i < n_in) ? in_sizes[i] : 0;
  }
  ca.off[13] = acc;
  convert_all_kernel<<<(acc + 255) / 256, 256, 0, stream>>>(ca, x_f, flag, acc);

  prep_kernel<<<1152, 256, 0, stream>>>(wqkv_f, wout_f, wm1_f, wm2_f, temp_f,
                                        wqkv_b, wout_b, wm1_b, wm2_b, qscale);

  gn_stats_kernel<<<256, 256, 0, stream>>>(x_f, part1);
  gn_apply_kernel<<<512, 256, 0, stream>>>(x_f, part1, g1_f, be1_f, xn_t);

  mfma_gemm<256, 4, 3, 0, 0><<<dim3(512, 3), 256, 0, stream>>>(
      wqkv_b, xn_t, qscale, nullptr, nullptr, qn, kn, vs, flag);

  attn5_kernel<<<dim3(64 * NCHUNK, NHEAD, NB), 256, 0, stream>>>(qn, kn, vs, pO, plb);
  attn_combine_kernel<<<1024, 256, 0, stream>>>(pO, plb, aout_t);

  mfma_gemm<256, 4, 1, 0, 0><<<dim3(512, 1), 256, 0, stream>>>(
      wout_b, aout_t, nullptr, bout_f, x_f, xres, nullptr, nullptr, flag);

  gn_stats_kernel<<<256, 256, 0, stream>>>(xres, part2);
  gn_apply_kernel<<<512, 256, 0, stream>>>(xres, part2, g2_f, be2_f, ybuf_t);

  mfma_gemm<256, 1, 0, 1, 64><<<dim3(512, 1), 256, 0, stream>>>(
      wm1_b, ybuf_t, nullptr, bm1_f, nullptr, h_t, nullptr, nullptr, flag);

  mfma_gemm<64, 4, 2, 0, 0><<<dim3(512, 1), 256, 0, stream>>>(
      wm2_b, h_t, nullptr, bm2_f, xres, d_out, nullptr, nullptr, flag);
}

// Round 8
// 261.201 us; speedup vs baseline: 1.4413x; 1.4413x over previous
//
#include <hip/hip_runtime.h>
#include <hip/hip_bf16.h>
#include <math.h>

// Problem constants (B=2, C=256, H=W=64, heads=8, hd=32, groups=32, hid=64)
#define NB 2
#define NC 256
#define NHEAD 8
#define HD 32
#define NPIX 4096
#define GEPS 1e-5f
#define NCHUNK 2          // j-split factor for attention (linear softmax => exact)
#define JLEN (NPIX / NCHUNK)

typedef short bf16x8 __attribute__((ext_vector_type(8)));
typedef float f32x4 __attribute__((ext_vector_type(4)));

typedef __attribute__((address_space(3))) unsigned int lds_u32;
typedef __attribute__((address_space(1))) const unsigned int glb_u32;

union U16x8 { uint4 u4; uint2 u2[2]; unsigned u32[4]; unsigned short us[8]; bf16x8 v; };

__device__ inline unsigned short tobf(float f) {  // round-to-nearest-even
  union { float f; unsigned u; } c; c.f = f;
  return (unsigned short)((c.u + 0x7FFFu + ((c.u >> 16) & 1u)) >> 16);
}
__device__ inline unsigned packtrunc(float lo, float hi) {  // truncating bf16 pack
  return (__float_as_uint(lo) >> 16) | (__float_as_uint(hi) & 0xFFFF0000u);
}

// ---------------------------------------------------------------------------
// Dtype detection (bf16 vs fp32 inputs).
// ---------------------------------------------------------------------------
__global__ void detect_kernel(const void* __restrict__ x, int* __restrict__ flag) {
  int lane = threadIdx.x;
  const unsigned short* u = (const unsigned short*)x;
  unsigned short h = u[2 * lane];
  unsigned e = (h >> 7) & 0xFFu;
  int weird = (e < 113u || e > 140u) ? 1 : 0;
  unsigned long long mask = __ballot(weird);
  if (lane == 0) flag[0] = (__popcll(mask) > 16) ? 0 : 1;
}

struct ConvArgs { const void* src[13]; int off[14]; };

__global__ __launch_bounds__(256) void convert_all_kernel(ConvArgs a, float* __restrict__ dstbase,
                                                          const int* __restrict__ flag, int total) {
  int i = blockIdx.x * 256 + threadIdx.x;
  if (i >= total) return;
  int s = 0;
  while (i >= a.off[s + 1]) ++s;
  int local = i - a.off[s];
  if (*flag) {
    unsigned v = ((const unsigned short*)a.src[s])[local];
    dstbase[i] = __uint_as_float(v << 16);
  } else {
    dstbase[i] = ((const float*)a.src[s])[local];
  }
}

// ---------------------------------------------------------------------------
// Prep: weights fp32->bf16 + qscale (temp*log2e for o<256 else 1).
// ---------------------------------------------------------------------------
__global__ __launch_bounds__(256) void prep_kernel(
    const float* __restrict__ wqkv, const float* __restrict__ wout,
    const float* __restrict__ wm1, const float* __restrict__ wm2,
    const float* __restrict__ temp,
    unsigned short* __restrict__ wqkv_b, unsigned short* __restrict__ wout_b,
    unsigned short* __restrict__ wm1_b, unsigned short* __restrict__ wm2_b,
    float* __restrict__ qscale) {
  int i = blockIdx.x * 256 + threadIdx.x;
  if (i < 196608) wqkv_b[i] = tobf(wqkv[i]);
  else if (i < 262144) wout_b[i - 196608] = tobf(wout[i - 196608]);
  else if (i < 278528) wm1_b[i - 262144] = tobf(wm1[i - 262144]);
  else if (i < 294912) wm2_b[i - 278528] = tobf(wm2[i - 278528]);
  if (i < 768) {
    if (i < 256) {
      float tc = fminf(fmaxf(temp[i >> 5], 1e-4f), 10.f);
      qscale[i] = tc * 1.4426950408889634f;
    } else qscale[i] = 1.0f;
  }
}

// ---------------------------------------------------------------------------
// GroupNorm stats, NO atomics: 256 blocks store deterministic partials.
// ---------------------------------------------------------------------------
__global__ __launch_bounds__(256) void gn_stats_kernel(const float* __restrict__ in,
                                                       float* __restrict__ part) {
  int blk = blockIdx.x;          // bg = blk>>2, quarter = blk&3
  int bg = blk >> 2, q = blk & 3;
  const float* base = in + (size_t)bg * 32768 + q * 8192;
  int t = threadIdx.x;
  float s = 0.f, s2 = 0.f;
  for (int i = t; i < 8192; i += 256) { float v = base[i]; s += v; s2 += v * v; }
  __shared__ float rs[256], rq[256];
  rs[t] = s; rq[t] = s2;
  __syncthreads();
  for (int o = 128; o > 0; o >>= 1) {
    if (t < o) { rs[t] += rs[t + o]; rq[t] += rq[t + o]; }
    __syncthreads();
  }
  if (t == 0) { part[blk * 2] = rs[0]; part[blk * 2 + 1] = rq[0]; }
}

// ---------------------------------------------------------------------------
// GroupNorm apply + transpose to bf16 pixel-major [p][256]. 512 blocks.
// ---------------------------------------------------------------------------
__global__ __launch_bounds__(256) void gn_apply_kernel(
    const float* __restrict__ in, const float* __restrict__ part,
    const float* __restrict__ gamma, const float* __restrict__ beta,
    unsigned short* __restrict__ outt) {
  int t = threadIdx.x;
  int p = blockIdx.x * 16 + (t & 15);
  int cg = t >> 4;
  int b = p >> 12, n = p & 4095;
  const float* src = in + ((size_t)b * NC + cg * 16) * NPIX + n;
  U16x8 lo, hi;
#pragma unroll
  for (int cc = 0; cc < 16; ++cc) {
    int c = cg * 16 + cc;
    int bg = b * 32 + (c >> 3);
    const float* pp = &part[bg * 8];   // [q][2] partials, q<4
    float s  = (pp[0] + pp[2]) + (pp[4] + pp[6]);
    float s2 = (pp[1] + pp[3]) + (pp[5] + pp[7]);
    float mean = s * (1.f / 32768.f);
    float inv = rsqrtf(s2 * (1.f / 32768.f) - mean * mean + GEPS);
    float gg = gamma[c] * inv;
    float vv = (src[(size_t)cc * NPIX] - mean) * gg + beta[c];
    if (cc < 8) lo.us[cc] = tobf(vv); else hi.us[cc - 8] = tobf(vv);
  }
  unsigned short* dst = outt + (size_t)p * NC + cg * 16;
  *(uint4*)dst = lo.u4;
  *(uint4*)(dst + 8) = hi.u4;
}

// ---------------------------------------------------------------------------
// bf16 MFMA GEMM, LDS-free (unchanged).
// ---------------------------------------------------------------------------
template <int K, int OT, int EPI, int ACT, int OSTR>
__global__ __launch_bounds__(256) void mfma_gemm(
    const unsigned short* __restrict__ W, const unsigned short* __restrict__ X,
    const float* __restrict__ scale, const float* __restrict__ bias,
    const float* __restrict__ res, void* __restrict__ out,
    void* __restrict__ out2, void* __restrict__ out3,
    const int* __restrict__ flag) {
  int t = threadIdx.x;
  int w = t >> 6, lane = t & 63, l16 = lane & 15, quad = lane >> 4;
  int p = blockIdx.x * 16 + l16;
  int ob = blockIdx.y * (64 * OT) + w * (16 * OT);
  const unsigned short* xrow = X + (size_t)p * K + quad * 8;
  f32x4 acc[OT] = {};
#pragma unroll
  for (int k0 = 0; k0 < K; k0 += 32) {
    U16x8 bfr; bfr.u4 = *(const uint4*)(xrow + k0);
#pragma unroll
    for (int ot = 0; ot < OT; ++ot) {
      U16x8 af;
      af.u4 = *(const uint4*)(W + (size_t)(ob + ot * 16 + l16) * K + k0 + quad * 8);
      acc[ot] = __builtin_amdgcn_mfma_f32_16x16x32_bf16(af.v, bfr.v, acc[ot], 0, 0, 0);
    }
  }
  int b = p >> 12, n = p & 4095;
  int wbf = (EPI == 2) ? *flag : 0;
#pragma unroll
  for (int ot = 0; ot < OT; ++ot) {
    int oc = ob + ot * 16 + quad * 4;
    float v[4];
#pragma unroll
    for (int r = 0; r < 4; ++r) {
      float vv = acc[ot][r];
      if (scale) vv *= scale[oc + r];
      if (bias) vv += bias[oc + r];
      if (ACT == 1) vv = 0.5f * vv * (1.f + erff(vv * 0.70710678118654752f));
      v[r] = vv;
    }
    if (EPI == 0) {
      uint2 pk;
      pk.x = (unsigned)tobf(v[0]) | ((unsigned)tobf(v[1]) << 16);
      pk.y = (unsigned)tobf(v[2]) | ((unsigned)tobf(v[3]) << 16);
      *(uint2*)((unsigned short*)out + (size_t)p * OSTR + oc) = pk;
    } else if (EPI == 3) {
      int sec = oc >> 8;  // block-uniform: 0=Q, 1=K, 2=V
      int c = oc & 255;
      if (sec < 2) {
        int hh = c >> 5, d = c & 31;
        unsigned short* base = (unsigned short*)(sec == 0 ? out : out2);
        uint2 pk;
        pk.x = (unsigned)tobf(v[0]) | ((unsigned)tobf(v[1]) << 16);
        pk.y = (unsigned)tobf(v[2]) | ((unsigned)tobf(v[3]) << 16);
        *(uint2*)(base + ((size_t)(b * NHEAD + hh) * NPIX + n) * HD + d) = pk;
      } else {
        unsigned short* vsb = (unsigned short*)out3;
#pragma unroll
        for (int r = 0; r < 4; ++r)
          vsb[((size_t)(b * NC + c + r)) * NPIX + n] = tobf(v[r]);
      }
    } else {
#pragma unroll
      for (int r = 0; r < 4; ++r) {
        size_t oidx = ((size_t)(b * NC + oc + r)) * NPIX + n;
        float vv = v[r] + res[oidx];
        if (EPI == 2) {
          if (wbf) ((__hip_bfloat16*)out)[oidx] = __float2bfloat16(vv);
          else ((float*)out)[oidx] = vv;
        } else {
          ((float*)out)[oidx] = vv;
        }
      }
    }
  }
}

// ---------------------------------------------------------------------------
// MFMA flash attention v6 — m97-style block-cooperative LDS staging.
// Per j-tile: all 4 waves async-DMA the SHARED 64x32 K tile (4KB) and 32x64
// V tile (4KB) into LDS via global_load_lds width=16 (1KB per wave-instr,
// 2 instrs/wave), barrier (drains vmcnt), compute S/exp/P/PV from LDS,
// barrier. Bank-conflict-free via SOURCE-side swizzle (DMA dest is
// wave-uniform+lane*16, so the permutation lives in the per-lane gptr):
//   K row j, unit p (16B) holds source d-quad g = p ^ ((j>>1)&3)
//   V row d, unit p holds source j-group g = p ^ (d&7)
// => all staged frag ds_read_b128 are <=2-way (free, m136).
// No per-wave prefetch regs => low VGPR => many blocks/CU cover the drain.
// ---------------------------------------------------------------------------
__global__ __launch_bounds__(256) void attn6_kernel(
    const unsigned short* __restrict__ qn, const unsigned short* __restrict__ kn,
    const unsigned short* __restrict__ vs, float* __restrict__ pO,
    float* __restrict__ pl) {
  int bx = blockIdx.x;
  int iblk = bx & 63, chunk = bx >> 6;
  int i0 = iblk * 64;
  int jbase = chunk * JLEN;
  int h = blockIdx.y, b = blockIdx.z;
  int bh = b * NHEAD + h;
  int t = threadIdx.x;
  int w = t >> 6, lane = t & 63, l16 = lane & 15, quad = lane >> 4;

  __shared__ unsigned short Kt[2048];      // [64 j][4 p][8] swizzled
  __shared__ unsigned short Vt[2048];      // [32 d][8 p][8] swizzled
  __shared__ unsigned short Pl[4][16][72];

  U16x8 qf;
  qf.u4 = *(const uint4*)(qn + ((size_t)bh * NPIX + i0 + w * 16 + l16) * HD + quad * 8);
  U16x8 ones;
#pragma unroll
  for (int j = 0; j < 8; ++j) ones.us[j] = 0x3F80;

  // DMA source pointers (per-lane; advance by 64 j per iteration).
  int kj = (w << 4) + (lane >> 2);                 // tile-local K row staged
  int kg = (lane & 3) ^ ((kj >> 1) & 3);           // swizzled source unit
  const unsigned short* kgp = kn + ((size_t)bh * NPIX + jbase + kj) * HD + kg * 8;
  int vd = (w << 3) + (lane >> 3);                 // tile-local V row staged
  int vg = (lane & 7) ^ (vd & 7);
  const unsigned short* vgp = vs + ((size_t)(b * NC + h * HD + vd)) * NPIX + jbase + vg * 8;
  // Wave-uniform LDS DMA destinations (HW adds lane*16).
  lds_u32* kdst = (lds_u32*)&Kt[w * 512];
  lds_u32* vdst = (lds_u32*)&Vt[w * 512];

  f32x4 o0 = {0.f, 0.f, 0.f, 0.f}, o1 = {0.f, 0.f, 0.f, 0.f};
  f32x4 lacc = {0.f, 0.f, 0.f, 0.f};
  const f32x4 zf = {0.f, 0.f, 0.f, 0.f};

  int sp = (quad ^ ((l16 >> 1) & 3)) * 8;          // K frag read swizzle
  for (int jt = 0; jt < JLEN; jt += 64) {
    __builtin_amdgcn_global_load_lds((glb_u32*)kgp, kdst, 16, 0, 0);
    __builtin_amdgcn_global_load_lds((glb_u32*)vgp, vdst, 16, 0, 0);
    kgp += 64 * HD;
    vgp += 64;
    __syncthreads();   // drains DMA (vmcnt 0) + all waves staged
    // S^T = K^T Q for this tile
    f32x4 st[4];
#pragma unroll
    for (int jj = 0; jj < 4; ++jj) {
      U16x8 kf; kf.u4 = *(const uint4*)&Kt[(jj * 16 + l16) * 32 + sp];
      st[jj] = __builtin_amdgcn_mfma_f32_16x16x32_bf16(kf.v, qf.v, zf, 0, 0, 0);
    }
#pragma unroll
    for (int jj = 0; jj < 4; ++jj) {
      uint2 pk;
      pk.x = packtrunc(__builtin_amdgcn_exp2f(st[jj][0]), __builtin_amdgcn_exp2f(st[jj][1]));
      pk.y = packtrunc(__builtin_amdgcn_exp2f(st[jj][2]), __builtin_amdgcn_exp2f(st[jj][3]));
      *(uint2*)&Pl[w][l16][jj * 16 + quad * 4] = pk;
    }
#pragma unroll
    for (int ks = 0; ks < 2; ++ks) {
      U16x8 pb; pb.u4 = *(const uint4*)&Pl[w][l16][ks * 32 + quad * 8];
      int vp = ((ks * 4 + quad) ^ (l16 & 7)) * 8;
      U16x8 va; va.u4 = *(const uint4*)&Vt[l16 * 64 + vp];
      U16x8 vb2; vb2.u4 = *(const uint4*)&Vt[(16 + l16) * 64 + vp];
      o0 = __builtin_amdgcn_mfma_f32_16x16x32_bf16(va.v, pb.v, o0, 0, 0, 0);
      o1 = __builtin_amdgcn_mfma_f32_16x16x32_bf16(vb2.v, pb.v, o1, 0, 0, 0);
      lacc = __builtin_amdgcn_mfma_f32_16x16x32_bf16(ones.v, pb.v, lacc, 0, 0, 0);
    }
    __syncthreads();   // all waves done reading Kt/Vt before next DMA
  }

  // Partial store. C-layout: col i = l16, rows d = quad*4+r (o0) / +16 (o1).
  int pr = bh * 64 + iblk;
  float* ob = pO + ((size_t)chunk * 1024 + pr) * 2048;
  int icol = w * 16 + l16;
#pragma unroll
  for (int r = 0; r < 4; ++r) {
    ob[(quad * 4 + r) * 64 + icol] = o0[r];
    ob[(16 + quad * 4 + r) * 64 + icol] = o1[r];
  }
  if (quad == 0)
    pl[((size_t)chunk * 1024 + pr) * 64 + icol] = lacc[0];
}

// ---------------------------------------------------------------------------
// Combine j-chunk partials: O = sum_c pO, l = sum_c pl; out = O/l -> bf16
// pixel-major aout_t[p][256]. Grid 1024.
// ---------------------------------------------------------------------------
__global__ __launch_bounds__(256) void attn_combine_kernel(
    const float* __restrict__ pO, const float* __restrict__ pl,
    unsigned short* __restrict__ aout_t) {
  int pr = blockIdx.x;
  int b = pr >> 9, h = (pr >> 6) & 7, iblk = pr & 63;
  int t = threadIdx.x;
  int i = t & 63, dg = t >> 6;
  float l = 0.f;
#pragma unroll
  for (int c = 0; c < NCHUNK; ++c) l += pl[((size_t)c * 1024 + pr) * 64 + i];
  float rinv = 1.f / l;
  U16x8 pk;
#pragma unroll
  for (int dd = 0; dd < 8; ++dd) {
    int d = dg * 8 + dd;
    float v = 0.f;
#pragma unroll
    for (int c = 0; c < NCHUNK; ++c)
      v += pO[((size_t)c * 1024 + pr) * 2048 + d * 64 + i];
    pk.us[dd] = tobf(v * rinv);
  }
  *(uint4*)(aout_t + ((size_t)b * NPIX + iblk * 64 + i) * NC + h * 32 + dg * 8) = pk.u4;
}

// ---------------------------------------------------------------------------
// Launch pipeline. (off is in FLOAT units; bf16 buffers advance by N/2.)
// ---------------------------------------------------------------------------
extern "C" void kernel_launch(void* const* d_in, const int* in_sizes, int n_in,
                              void* d_out, int out_size, void* d_ws, size_t ws_size,
                              hipStream_t stream) {
  float* ws = (float*)d_ws;
  int* flag = (int*)d_ws;
  size_t off = 16;
  float* x_f    = ws + off; off += (size_t)NB * NC * NPIX;
  float* wqkv_f = ws + off; off += 768 * 256;
  float* wout_f = ws + off; off += 256 * 256;
  float* bout_f = ws + off; off += 256;
  float* temp_f = ws + off; off += 8;
  float* g1_f   = ws + off; off += 256;
  float* be1_f  = ws + off; off += 256;
  float* g2_f   = ws + off; off += 256;
  float* be2_f  = ws + off; off += 256;
  float* wm1_f  = ws + off; off += 64 * 256;
  float* bm1_f  = ws + off; off += 64;
  float* wm2_f  = ws + off; off += 256 * 64;
  float* bm2_f  = ws + off; off += 256;
  float* xres   = ws + off; off += (size_t)NB * NC * NPIX;
  unsigned short* xn_t   = (unsigned short*)(ws + off); off += 1048576;  // [8192][256]
  unsigned short* qn     = (unsigned short*)(ws + off); off += 1048576;  // [16][4096][32]
  unsigned short* kn     = (unsigned short*)(ws + off); off += 1048576;  // [16][4096][32]
  unsigned short* vs     = (unsigned short*)(ws + off); off += 1048576;  // [2][256][4096]
  unsigned short* aout_t = (unsigned short*)(ws + off); off += 1048576;  // [8192][256]
  unsigned short* ybuf_t = (unsigned short*)(ws + off); off += 1048576;  // [8192][256]
  unsigned short* h_t    = (unsigned short*)(ws + off); off += 262144;   // [8192][64]
  unsigned short* wqkv_b = (unsigned short*)(ws + off); off += 98304;
  unsigned short* wout_b = (unsigned short*)(ws + off); off += 32768;
  unsigned short* wm1_b  = (unsigned short*)(ws + off); off += 8192;
  unsigned short* wm2_b  = (unsigned short*)(ws + off); off += 8192;
  float* qscale = ws + off; off += 768;
  float* part1  = ws + off; off += 512;   // GN1 partials [256][2]
  float* part2  = ws + off; off += 512;   // GN2 partials
  float* pO     = ws + off; off += (size_t)NCHUNK * 1024 * 2048;  // attn partial O
  float* plb    = ws + off; off += (size_t)NCHUNK * 1024 * 64;    // attn partial l

  detect_kernel<<<1, 64, 0, stream>>>(d_in[0], flag);

  ConvArgs ca;
  int acc = 0;
  for (int i = 0; i < 13; ++i) {
    ca.src[i] = d_in[i];
    ca.off[i] = acc;
    acc += (i < n_in) ? in_sizes[i] : 0;
  }
  ca.off[13] = acc;
  convert_all_kernel<<<(acc + 255) / 256, 256, 0, stream>>>(ca, x_f, flag, acc);

  prep_kernel<<<1152, 256, 0, stream>>>(wqkv_f, wout_f, wm1_f, wm2_f, temp_f,
                                        wqkv_b, wout_b, wm1_b, wm2_b, qscale);

  gn_stats_kernel<<<256, 256, 0, stream>>>(x_f, part1);
  gn_apply_kernel<<<512, 256, 0, stream>>>(x_f, part1, g1_f, be1_f, xn_t);

  mfma_gemm<256, 4, 3, 0, 0><<<dim3(512, 3), 256, 0, stream>>>(
      wqkv_b, xn_t, qscale, nullptr, nullptr, qn, kn, vs, flag);

  attn6_kernel<<<dim3(64 * NCHUNK, NHEAD, NB), 256, 0, stream>>>(qn, kn, vs, pO, plb);
  attn_combine_kernel<<<1024, 256, 0, stream>>>(pO, plb, aout_t);

  mfma_gemm<256, 4, 1, 0, 0><<<dim3(512, 1), 256, 0, stream>>>(
      wout_b, aout_t, nullptr, bout_f, x_f, xres, nullptr, nullptr, flag);

  gn_stats_kernel<<<256, 256, 0, stream>>>(xres, part2);
  gn_apply_kernel<<<512, 256, 0, stream>>>(xres, part2, g2_f, be2_f, ybuf_t);

  mfma_gemm<256, 1, 0, 1, 64><<<dim3(512, 1), 256, 0, stream>>>(
      wm1_b, ybuf_t, nullptr, bm1_f, nullptr, h_t, nullptr, nullptr, flag);

  mfma_gemm<64, 4, 2, 0, 0><<<dim3(512, 1), 256, 0, stream>>>(
      wm2_b, h_t, nullptr, bm2_f, xres, d_out, nullptr, nullptr, flag);
}

// Round 9
// 226.574 us; speedup vs baseline: 1.6615x; 1.1528x over previous
//
#include <hip/hip_runtime.h>
#include <hip/hip_bf16.h>
#include <math.h>

// Problem constants (B=2, C=256, H=W=64, heads=8, hd=32, groups=32, hid=64)
#define NB 2
#define NC 256
#define NHEAD 8
#define HD 32
#define NPIX 4096
#define GEPS 1e-5f
#define NCHUNK 2          // j-split factor for attention (linear softmax => exact)
#define JLEN (NPIX / NCHUNK)

typedef short bf16x8 __attribute__((ext_vector_type(8)));
typedef float f32x4 __attribute__((ext_vector_type(4)));

typedef __attribute__((address_space(3))) unsigned int lds_u32;
typedef __attribute__((address_space(1))) const unsigned int glb_u32;

union U16x8 { uint4 u4; uint2 u2[2]; unsigned u32[4]; unsigned short us[8]; bf16x8 v; };

__device__ inline unsigned short tobf(float f) {  // round-to-nearest-even
  union { float f; unsigned u; } c; c.f = f;
  return (unsigned short)((c.u + 0x7FFFu + ((c.u >> 16) & 1u)) >> 16);
}
__device__ inline unsigned packtrunc(float lo, float hi) {  // truncating bf16 pack, 1 instr
  return __builtin_amdgcn_perm(__float_as_uint(hi), __float_as_uint(lo), 0x07060302u);
}
__device__ inline float geluf(float v) {
  return 0.5f * v * (1.f + erff(v * 0.70710678118654752f));
}

// ---------------------------------------------------------------------------
// Dtype detection (bf16 vs fp32 inputs).
// ---------------------------------------------------------------------------
__global__ void detect_kernel(const void* __restrict__ x, int* __restrict__ flag) {
  int lane = threadIdx.x;
  const unsigned short* u = (const unsigned short*)x;
  unsigned short h = u[2 * lane];
  unsigned e = (h >> 7) & 0xFFu;
  int weird = (e < 113u || e > 140u) ? 1 : 0;
  unsigned long long mask = __ballot(weird);
  if (lane == 0) flag[0] = (__popcll(mask) > 16) ? 0 : 1;
}

struct ConvArgs { const void* src[13]; int off[14]; };

__device__ inline float ldsrc(const void* p, int idx, int bf) {
  if (bf) {
    unsigned v = ((const unsigned short*)p)[idx];
    return __uint_as_float(v << 16);
  }
  return ((const float*)p)[idx];
}

// ---------------------------------------------------------------------------
// Fused convert + prep + GN1 block-partials.
// - fp32 master copies of all 13 inputs (contiguous at dstbase)
// - x occupies blocks [0,8192): each block stores its {sum,sumsq} partial
//   (deterministic LDS tree, no atomics)
// - bf16 weights + qscale converted straight from SOURCE (flag-conditional)
// ---------------------------------------------------------------------------
__global__ __launch_bounds__(256) void conv_prep_kernel(
    ConvArgs a, float* __restrict__ dstbase, const int* __restrict__ flag,
    int total, unsigned short* __restrict__ wqkv_b, unsigned short* __restrict__ wout_b,
    unsigned short* __restrict__ wm1_b, unsigned short* __restrict__ wm2_b,
    float* __restrict__ qscale, float* __restrict__ part1p) {
  int blk = blockIdx.x, t = threadIdx.x;
  int i = blk * 256 + t;
  int bf = *flag;
  float val = 0.f;
  if (i < total) {
    int s = 0;
    while (i >= a.off[s + 1]) ++s;
    val = ldsrc(a.src[s], i - a.off[s], bf);
    dstbase[i] = val;
  }
  // GN1 partials (x = segment 0, exactly blocks 0..8191)
  __shared__ float rs[256], rq[256];
  int inx = (blk < 8192);
  rs[t] = inx ? val : 0.f;
  rq[t] = inx ? val * val : 0.f;
  __syncthreads();
  for (int o = 128; o > 0; o >>= 1) {
    if (t < o) { rs[t] += rs[t + o]; rq[t] += rq[t + o]; }
    __syncthreads();
  }
  if (t == 0 && inx) { part1p[blk * 2] = rs[0]; part1p[blk * 2 + 1] = rq[0]; }
  // prep (reads raw sources; independent of the fp32 copies)
  if (i < 196608) wqkv_b[i] = tobf(ldsrc(a.src[1], i, bf));
  else if (i < 262144) wout_b[i - 196608] = tobf(ldsrc(a.src[2], i - 196608, bf));
  else if (i < 278528) wm1_b[i - 262144] = tobf(ldsrc(a.src[9], i - 262144, bf));
  else if (i < 294912) wm2_b[i - 278528] = tobf(ldsrc(a.src[11], i - 278528, bf));
  if (i < 768) {
    if (i < 256) {
      float tc = fminf(fmaxf(ldsrc(a.src[4], i >> 5, bf), 1e-4f), 10.f);
      qscale[i] = tc * 1.4426950408889634f;
    } else qscale[i] = 1.0f;
  }
}

// ---------------------------------------------------------------------------
// QKV mega-kernel: GN1 partial-reduce -> normalize 16px x 256ch tile into LDS
// (bf16, pixel-major) -> K=256 GEMM (OT=6, grid y=2 splits the 768 outputs)
// -> EPI3 writes qn [bh][n][32] (pre-scaled temp*log2e), kn [bh][n][32],
// vs [b][c][n].
// ---------------------------------------------------------------------------
__global__ __launch_bounds__(256) void qkv_fused_kernel(
    const float* __restrict__ x_f, const float* __restrict__ part1p,
    const float* __restrict__ g1, const float* __restrict__ be1,
    const unsigned short* __restrict__ W, const float* __restrict__ qscale,
    unsigned short* __restrict__ qn, unsigned short* __restrict__ kn,
    unsigned short* __restrict__ vs) {
  int t = threadIdx.x;
  int w = t >> 6, lane = t & 63, l16 = lane & 15, quad = lane >> 4;
  int p0 = blockIdx.x * 16;
  int b = p0 >> 12;
  // Phase 1: finish GN1 stats (reduce 128 partials per group)
  __shared__ float red[32][8][2];
  __shared__ float sm[32], si[32];
  {
    int g = t >> 3, seg = t & 7;
    float s = 0.f, s2 = 0.f;
    const float* pp = part1p + ((size_t)(b * 32 + g) * 128 + seg * 16) * 2;
#pragma unroll
    for (int k = 0; k < 16; ++k) { s += pp[k * 2]; s2 += pp[k * 2 + 1]; }
    red[g][seg][0] = s; red[g][seg][1] = s2;
  }
  __syncthreads();
  if (t < 32) {
    float s = 0.f, s2 = 0.f;
#pragma unroll
    for (int k = 0; k < 8; ++k) { s += red[t][k][0]; s2 += red[t][k][1]; }
    float mean = s * (1.f / 32768.f);
    float var = s2 * (1.f / 32768.f) - mean * mean;
    sm[t] = mean; si[t] = rsqrtf(var + GEPS);
  }
  __syncthreads();
  // Phase 2: normalize tile -> Ys[p][256] bf16
  __shared__ unsigned short Ys[16][264];
  {
    int p = t & 15, cg = t >> 4;
    int n = (p0 & 4095) + p;
    const float* src = x_f + ((size_t)b * NC + cg * 16) * NPIX + n;
    U16x8 lo, hi;
#pragma unroll
    for (int cc = 0; cc < 16; ++cc) {
      int c = cg * 16 + cc;
      int g = c >> 3;
      float gg = g1[c] * si[g];
      float vv = (src[(size_t)cc * NPIX] - sm[g]) * gg + be1[c];
      if (cc < 8) lo.us[cc] = tobf(vv); else hi.us[cc - 8] = tobf(vv);
    }
    *(uint4*)&Ys[p][cg * 16] = lo.u4;
    *(uint4*)&Ys[p][cg * 16 + 8] = hi.u4;
  }
  __syncthreads();
  // Phase 3: GEMM, OT=6 (wave covers 96 outputs; y-block covers 384)
  int ob = blockIdx.y * 384 + w * 96;
  f32x4 acc[6] = {};
#pragma unroll
  for (int k0 = 0; k0 < 256; k0 += 32) {
    U16x8 bfr; bfr.u4 = *(const uint4*)&Ys[l16][k0 + quad * 8];
#pragma unroll
    for (int ot = 0; ot < 6; ++ot) {
      U16x8 af;
      af.u4 = *(const uint4*)(W + (size_t)(ob + ot * 16 + l16) * 256 + k0 + quad * 8);
      acc[ot] = __builtin_amdgcn_mfma_f32_16x16x32_bf16(af.v, bfr.v, acc[ot], 0, 0, 0);
    }
  }
  int n = (p0 & 4095) + l16;
#pragma unroll
  for (int ot = 0; ot < 6; ++ot) {
    int oc = ob + ot * 16 + quad * 4;
    float v[4];
#pragma unroll
    for (int r = 0; r < 4; ++r) v[r] = acc[ot][r] * qscale[oc + r];
    int sec = oc >> 8;  // per-ot uniform: 0=Q, 1=K, 2=V
    int c = oc & 255;
    if (sec < 2) {
      int hh = c >> 5, d = c & 31;
      unsigned short* base = sec == 0 ? qn : kn;
      uint2 pk;
      pk.x = (unsigned)tobf(v[0]) | ((unsigned)tobf(v[1]) << 16);
      pk.y = (unsigned)tobf(v[2]) | ((unsigned)tobf(v[3]) << 16);
      *(uint2*)(base + ((size_t)(b * NHEAD + hh) * NPIX + n) * HD + d) = pk;
    } else {
#pragma unroll
      for (int r = 0; r < 4; ++r)
        vs[((size_t)(b * NC + c + r)) * NPIX + n] = tobf(v[r]);
    }
  }
}

// ---------------------------------------------------------------------------
// MFMA flash attention v6 (round-8 proven): block-cooperative LDS staging via
// global_load_lds width=16, source-side swizzles, j-split partials.
// ---------------------------------------------------------------------------
__global__ __launch_bounds__(256) void attn6_kernel(
    const unsigned short* __restrict__ qn, const unsigned short* __restrict__ kn,
    const unsigned short* __restrict__ vs, float* __restrict__ pO,
    float* __restrict__ pl) {
  int bx = blockIdx.x;
  int iblk = bx & 63, chunk = bx >> 6;
  int i0 = iblk * 64;
  int jbase = chunk * JLEN;
  int h = blockIdx.y, b = blockIdx.z;
  int bh = b * NHEAD + h;
  int t = threadIdx.x;
  int w = t >> 6, lane = t & 63, l16 = lane & 15, quad = lane >> 4;

  __shared__ unsigned short Kt[2048];      // [64 j][4 p][8] swizzled
  __shared__ unsigned short Vt[2048];      // [32 d][8 p][8] swizzled
  __shared__ unsigned short Pl[4][16][72];

  U16x8 qf;
  qf.u4 = *(const uint4*)(qn + ((size_t)bh * NPIX + i0 + w * 16 + l16) * HD + quad * 8);
  U16x8 ones;
#pragma unroll
  for (int j = 0; j < 8; ++j) ones.us[j] = 0x3F80;

  int kj = (w << 4) + (lane >> 2);
  int kg = (lane & 3) ^ ((kj >> 1) & 3);
  const unsigned short* kgp = kn + ((size_t)bh * NPIX + jbase + kj) * HD + kg * 8;
  int vd = (w << 3) + (lane >> 3);
  int vg = (lane & 7) ^ (vd & 7);
  const unsigned short* vgp = vs + ((size_t)(b * NC + h * HD + vd)) * NPIX + jbase + vg * 8;
  lds_u32* kdst = (lds_u32*)&Kt[w * 512];
  lds_u32* vdst = (lds_u32*)&Vt[w * 512];

  f32x4 o0 = {0.f, 0.f, 0.f, 0.f}, o1 = {0.f, 0.f, 0.f, 0.f};
  f32x4 lacc = {0.f, 0.f, 0.f, 0.f};
  const f32x4 zf = {0.f, 0.f, 0.f, 0.f};

  int sp = (quad ^ ((l16 >> 1) & 3)) * 8;
  for (int jt = 0; jt < JLEN; jt += 64) {
    __builtin_amdgcn_global_load_lds((glb_u32*)kgp, kdst, 16, 0, 0);
    __builtin_amdgcn_global_load_lds((glb_u32*)vgp, vdst, 16, 0, 0);
    kgp += 64 * HD;
    vgp += 64;
    __syncthreads();
    f32x4 st[4];
#pragma unroll
    for (int jj = 0; jj < 4; ++jj) {
      U16x8 kf; kf.u4 = *(const uint4*)&Kt[(jj * 16 + l16) * 32 + sp];
      st[jj] = __builtin_amdgcn_mfma_f32_16x16x32_bf16(kf.v, qf.v, zf, 0, 0, 0);
    }
#pragma unroll
    for (int jj = 0; jj < 4; ++jj) {
      uint2 pk;
      pk.x = packtrunc(__builtin_amdgcn_exp2f(st[jj][0]), __builtin_amdgcn_exp2f(st[jj][1]));
      pk.y = packtrunc(__builtin_amdgcn_exp2f(st[jj][2]), __builtin_amdgcn_exp2f(st[jj][3]));
      *(uint2*)&Pl[w][l16][jj * 16 + quad * 4] = pk;
    }
#pragma unroll
    for (int ks = 0; ks < 2; ++ks) {
      U16x8 pb; pb.u4 = *(const uint4*)&Pl[w][l16][ks * 32 + quad * 8];
      int vp = ((ks * 4 + quad) ^ (l16 & 7)) * 8;
      U16x8 va; va.u4 = *(const uint4*)&Vt[l16 * 64 + vp];
      U16x8 vb2; vb2.u4 = *(const uint4*)&Vt[(16 + l16) * 64 + vp];
      o0 = __builtin_amdgcn_mfma_f32_16x16x32_bf16(va.v, pb.v, o0, 0, 0, 0);
      o1 = __builtin_amdgcn_mfma_f32_16x16x32_bf16(vb2.v, pb.v, o1, 0, 0, 0);
      lacc = __builtin_amdgcn_mfma_f32_16x16x32_bf16(ones.v, pb.v, lacc, 0, 0, 0);
    }
    __syncthreads();
  }

  int pr = bh * 64 + iblk;
  float* ob = pO + ((size_t)chunk * 1024 + pr) * 2048;
  int icol = w * 16 + l16;
#pragma unroll
  for (int r = 0; r < 4; ++r) {
    ob[(quad * 4 + r) * 64 + icol] = o0[r];
    ob[(16 + quad * 4 + r) * 64 + icol] = o1[r];
  }
  if (quad == 0)
    pl[((size_t)chunk * 1024 + pr) * 64 + icol] = lacc[0];
}

// ---------------------------------------------------------------------------
// Combine j-chunk partials -> bf16 pixel-major aout_t[p][256].
// ---------------------------------------------------------------------------
__global__ __launch_bounds__(256) void attn_combine_kernel(
    const float* __restrict__ pO, const float* __restrict__ pl,
    unsigned short* __restrict__ aout_t) {
  int pr = blockIdx.x;
  int b = pr >> 9, h = (pr >> 6) & 7, iblk = pr & 63;
  int t = threadIdx.x;
  int i = t & 63, dg = t >> 6;
  float l = 0.f;
#pragma unroll
  for (int c = 0; c < NCHUNK; ++c) l += pl[((size_t)c * 1024 + pr) * 64 + i];
  float rinv = 1.f / l;
  U16x8 pk;
#pragma unroll
  for (int dd = 0; dd < 8; ++dd) {
    int d = dg * 8 + dd;
    float v = 0.f;
#pragma unroll
    for (int c = 0; c < NCHUNK; ++c)
      v += pO[((size_t)c * 1024 + pr) * 2048 + d * 64 + i];
    pk.us[dd] = tobf(v * rinv);
  }
  *(uint4*)(aout_t + ((size_t)b * NPIX + iblk * 64 + i) * NC + h * 32 + dg * 8) = pk.u4;
}

// ---------------------------------------------------------------------------
// wout GEMM (K=256, OT=4) + bias + residual(x) -> xres fp32 channel-major,
// AND per-block GN2 partials (16px x 8ch per group, deterministic).
// ---------------------------------------------------------------------------
__global__ __launch_bounds__(256) void wout_kernel(
    const unsigned short* __restrict__ W, const unsigned short* __restrict__ X,
    const float* __restrict__ bias, const float* __restrict__ res,
    float* __restrict__ xres, float* __restrict__ part2p) {
  int t = threadIdx.x;
  int w = t >> 6, lane = t & 63, l16 = lane & 15, quad = lane >> 4;
  int p = blockIdx.x * 16 + l16;
  int ob = w * 64;
  const unsigned short* xrow = X + (size_t)p * 256 + quad * 8;
  f32x4 acc[4] = {};
#pragma unroll
  for (int k0 = 0; k0 < 256; k0 += 32) {
    U16x8 bfr; bfr.u4 = *(const uint4*)(xrow + k0);
#pragma unroll
    for (int ot = 0; ot < 4; ++ot) {
      U16x8 af;
      af.u4 = *(const uint4*)(W + (size_t)(ob + ot * 16 + l16) * 256 + k0 + quad * 8);
      acc[ot] = __builtin_amdgcn_mfma_f32_16x16x32_bf16(af.v, bfr.v, acc[ot], 0, 0, 0);
    }
  }
  int b = p >> 12, n = p & 4095;
  __shared__ float sb[256][4][2];
#pragma unroll
  for (int ot = 0; ot < 4; ++ot) {
    int oc = ob + ot * 16 + quad * 4;
    float s = 0.f, s2 = 0.f;
#pragma unroll
    for (int r = 0; r < 4; ++r) {
      size_t oidx = ((size_t)(b * NC + oc + r)) * NPIX + n;
      float vv = acc[ot][r] + bias[oc + r] + res[oidx];
      xres[oidx] = vv;
      s += vv; s2 += vv * vv;
    }
    sb[t][ot][0] = s; sb[t][ot][1] = s2;
  }
  __syncthreads();
  if (t < 32) {  // group index g == t; channels [g*8, g*8+8)
    int ww = t >> 3, rem = t & 7, ot = rem >> 1, qp = rem & 1;
    float s = 0.f, s2 = 0.f;
#pragma unroll
    for (int q = 2 * qp; q < 2 * qp + 2; ++q)
      for (int l = 0; l < 16; ++l) {
        int tt = ww * 64 + q * 16 + l;
        s += sb[tt][ot][0]; s2 += sb[tt][ot][1];
      }
    size_t idx = ((size_t)(b * 32 + t) * 256 + (blockIdx.x & 255)) * 2;
    part2p[idx] = s; part2p[idx + 1] = s2;
  }
}

// ---------------------------------------------------------------------------
// MLP mega-kernel: GN2 finish -> normalize (xres tile cached in LDS) ->
// MLP1 (K=256) + GELU -> Hs -> MLP2 (K=64, OT=4) + bias + residual(LDS) ->
// final store (flag dtype), channel-major.
// ---------------------------------------------------------------------------
__global__ __launch_bounds__(256) void mlp_fused_kernel(
    const float* __restrict__ xres, const float* __restrict__ part2p,
    const float* __restrict__ g2, const float* __restrict__ be2,
    const unsigned short* __restrict__ W1, const float* __restrict__ b1,
    const unsigned short* __restrict__ W2, const float* __restrict__ b2,
    void* __restrict__ dout, const int* __restrict__ flag) {
  int t = threadIdx.x;
  int w = t >> 6, lane = t & 63, l16 = lane & 15, quad = lane >> 4;
  int p0 = blockIdx.x * 16;
  int b = p0 >> 12;
  __shared__ float red[32][8][2];
  __shared__ float sm[32], si[32];
  {
    int g = t >> 3, seg = t & 7;
    float s = 0.f, s2 = 0.f;
    const float* pp = part2p + ((size_t)(b * 32 + g) * 256 + seg * 32) * 2;
#pragma unroll
    for (int k = 0; k < 32; ++k) { s += pp[k * 2]; s2 += pp[k * 2 + 1]; }
    red[g][seg][0] = s; red[g][seg][1] = s2;
  }
  __syncthreads();
  if (t < 32) {
    float s = 0.f, s2 = 0.f;
#pragma unroll
    for (int k = 0; k < 8; ++k) { s += red[t][k][0]; s2 += red[t][k][1]; }
    float mean = s * (1.f / 32768.f);
    float var = s2 * (1.f / 32768.f) - mean * mean;
    sm[t] = mean; si[t] = rsqrtf(var + GEPS);
  }
  __syncthreads();
  __shared__ float Xs[16][261];           // raw xres tile (residual source)
  __shared__ unsigned short Ys[16][264];  // normalized bf16 tile
  {
    int p = t & 15, cg = t >> 4;
    int n = (p0 & 4095) + p;
    const float* src = xres + ((size_t)b * NC + cg * 16) * NPIX + n;
    U16x8 lo, hi;
#pragma unroll
    for (int cc = 0; cc < 16; ++cc) {
      int c = cg * 16 + cc;
      int g = c >> 3;
      float v = src[(size_t)cc * NPIX];
      Xs[p][c] = v;
      float yv = (v - sm[g]) * (g2[c] * si[g]) + be2[c];
      if (cc < 8) lo.us[cc] = tobf(yv); else hi.us[cc - 8] = tobf(yv);
    }
    *(uint4*)&Ys[p][cg * 16] = lo.u4;
    *(uint4*)&Ys[p][cg * 16 + 8] = hi.u4;
  }
  __syncthreads();
  // MLP1: K=256, M=64; wave w covers oc [w*16, w*16+16)
  f32x4 a1 = {0.f, 0.f, 0.f, 0.f};
#pragma unroll
  for (int k0 = 0; k0 < 256; k0 += 32) {
    U16x8 bfr; bfr.u4 = *(const uint4*)&Ys[l16][k0 + quad * 8];
    U16x8 af;
    af.u4 = *(const uint4*)(W1 + (size_t)(w * 16 + l16) * 256 + k0 + quad * 8);
    a1 = __builtin_amdgcn_mfma_f32_16x16x32_bf16(af.v, bfr.v, a1, 0, 0, 0);
  }
  __shared__ unsigned short Hs[16][72];
  {
    int oc = w * 16 + quad * 4;
    float h0 = geluf(a1[0] + b1[oc]),     h1 = geluf(a1[1] + b1[oc + 1]);
    float h2 = geluf(a1[2] + b1[oc + 2]), h3 = geluf(a1[3] + b1[oc + 3]);
    uint2 pk;
    pk.x = (unsigned)tobf(h0) | ((unsigned)tobf(h1) << 16);
    pk.y = (unsigned)tobf(h2) | ((unsigned)tobf(h3) << 16);
    *(uint2*)&Hs[l16][oc] = pk;
  }
  __syncthreads();
  // MLP2: K=64, OT=4; wave w covers oc [w*64, (w+1)*64)
  f32x4 a2[4] = {};
#pragma unroll
  for (int k0 = 0; k0 < 64; k0 += 32) {
    U16x8 bfr; bfr.u4 = *(const uint4*)&Hs[l16][k0 + quad * 8];
#pragma unroll
    for (int ot = 0; ot < 4; ++ot) {
      U16x8 af;
      af.u4 = *(const uint4*)(W2 + (size_t)(w * 64 + ot * 16 + l16) * 64 + k0 + quad * 8);
      a2[ot] = __builtin_amdgcn_mfma_f32_16x16x32_bf16(af.v, bfr.v, a2[ot], 0, 0, 0);
    }
  }
  int n = (p0 & 4095) + l16;
  int wbf = *flag;
#pragma unroll
  for (int ot = 0; ot < 4; ++ot) {
    int oc = w * 64 + ot * 16 + quad * 4;
#pragma unroll
    for (int r = 0; r < 4; ++r) {
      float v = a2[ot][r] + b2[oc + r] + Xs[l16][oc + r];
      size_t oidx = ((size_t)(b * NC + oc + r)) * NPIX + n;
      if (wbf) ((__hip_bfloat16*)dout)[oidx] = __float2bfloat16(v);
      else ((float*)dout)[oidx] = v;
    }
  }
}

// ---------------------------------------------------------------------------
// Launch pipeline: 7 kernels.
// ---------------------------------------------------------------------------
extern "C" void kernel_launch(void* const* d_in, const int* in_sizes, int n_in,
                              void* d_out, int out_size, void* d_ws, size_t ws_size,
                              hipStream_t stream) {
  float* ws = (float*)d_ws;
  int* flag = (int*)d_ws;
  size_t off = 16;
  // fp32 master copies (contiguous convert target; keep full layout):
  float* x_f    = ws + off; off += (size_t)NB * NC * NPIX;
  float* wqkv_f = ws + off; off += 768 * 256;
  float* wout_f = ws + off; off += 256 * 256;
  float* bout_f = ws + off; off += 256;
  float* temp_f = ws + off; off += 8;
  float* g1_f   = ws + off; off += 256;
  float* be1_f  = ws + off; off += 256;
  float* g2_f   = ws + off; off += 256;
  float* be2_f  = ws + off; off += 256;
  float* wm1_f  = ws + off; off += 64 * 256;
  float* bm1_f  = ws + off; off += 64;
  float* wm2_f  = ws + off; off += 256 * 64;
  float* bm2_f  = ws + off; off += 256;
  float* xres   = ws + off; off += (size_t)NB * NC * NPIX;
  unsigned short* qn     = (unsigned short*)(ws + off); off += 1048576;  // [16][4096][32]
  unsigned short* kn     = (unsigned short*)(ws + off); off += 1048576;  // [16][4096][32]
  unsigned short* vs     = (unsigned short*)(ws + off); off += 1048576;  // [2][256][4096]
  unsigned short* aout_t = (unsigned short*)(ws + off); off += 1048576;  // [8192][256]
  unsigned short* wqkv_b = (unsigned short*)(ws + off); off += 98304;
  unsigned short* wout_b = (unsigned short*)(ws + off); off += 32768;
  unsigned short* wm1_b  = (unsigned short*)(ws + off); off += 8192;
  unsigned short* wm2_b  = (unsigned short*)(ws + off); off += 8192;
  float* qscale = ws + off; off += 768;
  float* part1p = ws + off; off += 16384;   // [8192][2] GN1 block partials
  float* part2p = ws + off; off += 65536;   // [128 bg][256 blk][2] GN2 partials
  float* pO     = ws + off; off += (size_t)NCHUNK * 1024 * 2048;
  float* plb    = ws + off; off += (size_t)NCHUNK * 1024 * 64;
  (void)wqkv_f; (void)wout_f; (void)wm1_f; (void)wm2_f; (void)temp_f; (void)bm1_f;

  detect_kernel<<<1, 64, 0, stream>>>(d_in[0], flag);

  ConvArgs ca;
  int acc = 0;
  for (int i = 0; i < 13; ++i) {
    ca.src[i] = d_in[i];
    ca.off[i] = acc;
    acc += (i < n_in) ? in_sizes[i] : 0;
  }
  ca.off[13] = acc;
  conv_prep_kernel<<<(acc + 255) / 256, 256, 0, stream>>>(
      ca, x_f, flag, acc, wqkv_b, wout_b, wm1_b, wm2_b, qscale, part1p);

  qkv_fused_kernel<<<dim3(512, 2), 256, 0, stream>>>(
      x_f, part1p, g1_f, be1_f, wqkv_b, qscale, qn, kn, vs);

  attn6_kernel<<<dim3(64 * NCHUNK, NHEAD, NB), 256, 0, stream>>>(qn, kn, vs, pO, plb);
  attn_combine_kernel<<<1024, 256, 0, stream>>>(pO, plb, aout_t);

  wout_kernel<<<512, 256, 0, stream>>>(wout_b, aout_t, bout_f, x_f, xres, part2p);

  mlp_fused_kernel<<<512, 256, 0, stream>>>(
      xres, part2p, g2_f, be2_f, wm1_b, bm1_f, wm2_b, bm2_f, d_out, flag);
}